// Round 11
// baseline (359.043 us; speedup 1.0000x reference)
//
#include <hip/hip_runtime.h>

// PointSetDifferenceModule: B=4, N=8192, C=64, K=16
// Round 11: XCD-affinity gather mapping (blockIdx&7 -> (dir,batch) so each XCD's
// gathers stay in one 4MB batch slice, which fits its private L2), plus
// unguarded stat accumulation (mask only at LDS write).
// FT row (512B): [ f fp32 x64 | G_d bf16 x64 | G_s bf16 x64 ]

#define Bn 4
#define Nn 8192
#define NPTS (Bn * Nn)        // 32768
#define NSAMP (NPTS * 16)     // 524288
#define EPSf 1e-5f
#define FT_STRIDE 512
#define GSZ (NPTS * 64)

typedef __attribute__((ext_vector_type(8))) short v8bf;
typedef __attribute__((ext_vector_type(4))) float v4f;

__device__ inline unsigned pack_bf16x2(float a, float b) {
  unsigned ua = __float_as_uint(a), ub = __float_as_uint(b);
  ua = (ua + 0x7FFFu + ((ua >> 16) & 1u)) >> 16;
  ub = (ub + 0x7FFFu + ((ub >> 16) & 1u)) >> 16;
  return (ub << 16) | ua;
}
__device__ inline float bf16_lo(unsigned u) { return __uint_as_float(u << 16); }
__device__ inline float bf16_hi(unsigned u) { return __uint_as_float(u & 0xFFFF0000u); }

// ---------------- build fused tables: f fp32 + G_d, G_s bf16 ----------------
__global__ __launch_bounds__(256) void gemmG(const float* __restrict__ f0,
                                             const float* __restrict__ f1,
                                             const float* __restrict__ wd,
                                             const float* __restrict__ wsim,
                                             char* __restrict__ FT0,
                                             char* __restrict__ FT1) {
  int z = blockIdx.z;
  const float* F = z ? f1 : f0;
  char* FT = z ? FT1 : FT0;
  __shared__ float Fl[64][65];
  __shared__ float Wd[64][65];
  __shared__ float Ws[64][65];
  int t = threadIdx.x;
#pragma unroll
  for (int i = 0; i < 16; i++) {
    int ix = t + i * 256;
    Wd[ix >> 6][ix & 63] = wd[ix];
    Ws[ix >> 6][ix & 63] = wsim[ix];
  }
  int ptb = blockIdx.x * 64;
#pragma unroll
  for (int i = 0; i < 16; i++) {
    int ix = t + i * 256;
    float v = F[(size_t)ptb * 64 + ix];
    Fl[ix >> 6][ix & 63] = v;
    *(float*)(FT + (size_t)(ptb + (ix >> 6)) * FT_STRIDE + (ix & 63) * 4) = v;
  }
  __syncthreads();
  int ty = t >> 4, tx = t & 15, r0 = ty * 4, c0 = tx * 4;
  float ad[4][4] = {}, as_[4][4] = {};
#pragma unroll 4
  for (int j = 0; j < 64; ++j) {
    float a[4], w1[4], w2[4];
#pragma unroll
    for (int i = 0; i < 4; i++) a[i] = Fl[r0 + i][j];
#pragma unroll
    for (int m = 0; m < 4; m++) {
      w1[m] = Wd[c0 + m][j];
      w2[m] = Ws[c0 + m][j];
    }
#pragma unroll
    for (int i = 0; i < 4; i++)
#pragma unroll
      for (int m = 0; m < 4; m++) {
        ad[i][m] += a[i] * w1[m];
        as_[i][m] += a[i] * w2[m];
      }
  }
#pragma unroll
  for (int i = 0; i < 4; i++) {
    char* row = FT + (size_t)(ptb + r0 + i) * FT_STRIDE;
    uint2 gd2 = make_uint2(pack_bf16x2(ad[i][0], ad[i][1]),
                           pack_bf16x2(ad[i][2], ad[i][3]));
    *(uint2*)(row + 256 + c0 * 2) = gd2;
    uint2 gs2 = make_uint2(pack_bf16x2(as_[i][0], as_[i][1]),
                           pack_bf16x2(as_[i][2], as_[i][3]));
    *(uint2*)(row + 384 + c0 * 2) = gs2;
  }
}

// ---------------- diff stats + sim softmax + y_sim (one wave per point) ----------------
// lane 0-31: f pairs | lane 32-47: gd x4 | lane 48-63: gs x4
// XCD affinity: unit = blockIdx.x & 7 -> (dir, batch); each XCD gathers from one
// 4MB FO batch slice.
__global__ __launch_bounds__(256) void stats_sim(
    const char* __restrict__ FT0, const char* __restrict__ FT1,
    const int* __restrict__ i01, const int* __restrict__ i10,
    float* __restrict__ YS0, float* __restrict__ YS1, float* __restrict__ acc) {
  int u = blockIdx.x & 7;
  int dir = u & 1, batch = u >> 1;
  const char* FS = dir ? FT1 : FT0;
  const char* FO = dir ? FT0 : FT1;
  const int* idx = dir ? i10 : i01;
  float* ys = dir ? YS1 : YS0;
  float* accDiff = acc + dir * 128;
  float* accSim = acc + 256 + dir * 128;
  int lane = threadIdx.x & 63, wave = threadIdx.x >> 6;
  int w = blockIdx.x >> 3;              // 0..511
  int gw = w * 4 + wave;                // 0..2047
  int ptbase = batch * Nn + gw * 4;     // 4 consecutive points per wave
  int bbase = batch * Nn;
  bool isD = (lane >= 32) && (lane < 48);
  bool isS = lane >= 48;
  int lq = lane & 15;
  float sdl[4] = {0, 0, 0, 0}, qdl[4] = {0, 0, 0, 0};
  float ssl[4] = {0, 0, 0, 0}, qsl[4] = {0, 0, 0, 0};
#pragma unroll
  for (int pi = 0; pi < 4; pi++) {
    int ptu = ptbase + pi;  // wave-uniform
    const char* srow = FS + (size_t)ptu * FT_STRIDE;
    uint2 selfr = *(const uint2*)(srow + lane * 8);
    const int* ip = idx + ptu * 16;
    int jx[16];
#pragma unroll
    for (int k = 0; k < 16; k++) jx[k] = ip[k];
    const char* ob = FO + (size_t)bbase * FT_STRIDE;
    uint2 nb[16];
#pragma unroll
    for (int k = 0; k < 16; k++)
      nb[k] = *(const uint2*)(ob + (size_t)jx[k] * FT_STRIDE + lane * 8);
    float fsx = __uint_as_float(selfr.x), fsy = __uint_as_float(selfr.y);
    float gds0 = bf16_lo(selfr.x), gds1 = bf16_hi(selfr.x);
    float gds2 = bf16_lo(selfr.y), gds3 = bf16_hi(selfr.y);
    float sims[16];
#pragma unroll
    for (int k = 0; k < 16; k++) {
      float p = fsx * __uint_as_float(nb[k].x) + fsy * __uint_as_float(nb[k].y);
      p += __shfl_xor(p, 16);
      p += __shfl_xor(p, 8);
      p += __shfl_xor(p, 4);
      p += __shfl_xor(p, 2);
      p += __shfl_xor(p, 1);
      sims[k] = __uint_as_float(__builtin_amdgcn_readfirstlane(__float_as_uint(p)));
      // unguarded accumulation: only lanes 32-47's values are ever read
      float y0 = gds0 - bf16_lo(nb[k].x);
      float y1 = gds1 - bf16_hi(nb[k].x);
      float y2 = gds2 - bf16_lo(nb[k].y);
      float y3 = gds3 - bf16_hi(nb[k].y);
      sdl[0] += y0; qdl[0] += y0 * y0;
      sdl[1] += y1; qdl[1] += y1 * y1;
      sdl[2] += y2; qdl[2] += y2 * y2;
      sdl[3] += y3; qdl[3] += y3 * y3;
    }
    float mmax = sims[0];
#pragma unroll
    for (int k = 1; k < 16; k++) mmax = fmaxf(mmax, sims[k]);
    float den = 0.f, ya0 = 0.f, ya1 = 0.f, ya2 = 0.f, ya3 = 0.f;
#pragma unroll
    for (int k = 0; k < 16; k++) {
      float e = __expf(sims[k] - mmax);
      den += e;
      ya0 += e * bf16_lo(nb[k].x);
      ya1 += e * bf16_hi(nb[k].x);
      ya2 += e * bf16_lo(nb[k].y);
      ya3 += e * bf16_hi(nb[k].y);
    }
    float inv = 1.f / den;
    ya0 *= inv; ya1 *= inv; ya2 *= inv; ya3 *= inv;
    if (isS)
      *(float4*)(ys + (size_t)ptu * 64 + lq * 4) = make_float4(ya0, ya1, ya2, ya3);
    ssl[0] += ya0; qsl[0] += ya0 * ya0;
    ssl[1] += ya1; qsl[1] += ya1 * ya1;
    ssl[2] += ya2; qsl[2] += ya2 * ya2;
    ssl[3] += ya3; qsl[3] += ya3 * ya3;
  }
  __shared__ float rA[4][64], rB[4][64], rC[4][64], rD2[4][64];
  int cd = lq * 4;
  if (isD) {
#pragma unroll
    for (int i = 0; i < 4; i++) {
      rA[wave][cd + i] = sdl[i];
      rB[wave][cd + i] = qdl[i];
    }
  }
  if (isS) {
#pragma unroll
    for (int i = 0; i < 4; i++) {
      rC[wave][cd + i] = ssl[i];
      rD2[wave][cd + i] = qsl[i];
    }
  }
  __syncthreads();
  if (wave == 0) {
    float v = rA[0][lane] + rA[1][lane] + rA[2][lane] + rA[3][lane];
    atomicAdd(accDiff + lane, v);
    v = rB[0][lane] + rB[1][lane] + rB[2][lane] + rB[3][lane];
    atomicAdd(accDiff + 64 + lane, v);
    v = rC[0][lane] + rC[1][lane] + rC[2][lane] + rC[3][lane];
    atomicAdd(accSim + lane, v);
    v = rD2[0][lane] + rD2[1][lane] + rD2[2][lane] + rD2[3][lane];
    atomicAdd(accSim + 64 + lane, v);
  }
}

// ---------------- finalize diff0,diff1,sim0,sim1 ----------------
__global__ void finalize1(const float* __restrict__ acc, const float* __restrict__ dg,
                          const float* __restrict__ dbeta, const float* __restrict__ sg,
                          const float* __restrict__ sbeta, float* __restrict__ ss) {
  int t = threadIdx.x;
  int seg = t >> 6, c = t & 63;
  const float* a = acc + seg * 128;
  float cnt = (seg < 2) ? (float)NSAMP : (float)NPTS;
  float mu = a[c] / cnt;
  float var = a[64 + c] / cnt - mu * mu;
  const float* g = (seg < 2) ? dg : sg;
  const float* be = (seg < 2) ? dbeta : sbeta;
  float scale = g[c] * rsqrtf(var + EPSf);
  ss[seg * 128 + c] = scale;
  ss[seg * 128 + 64 + c] = be[c] - mu * scale;
}

// ---------------- diff output: gather bf16 + BN/relu + MFMA GEMM + max over K --------
// Same XCD-affinity mapping: unit = blockIdx.x & 7 -> (dir,batch); 4 tiles/block.
__global__ __launch_bounds__(256) void diff_out_k(
    const char* __restrict__ FT0, const char* __restrict__ FT1,
    const int* __restrict__ i01, const int* __restrict__ i10,
    const float* __restrict__ w2d, const float* __restrict__ b2d,
    const float* __restrict__ ss, float* __restrict__ DF0, float* __restrict__ DF1) {
  int u = blockIdx.x & 7;
  int dir = u & 1, batch = u >> 1;
  const char* FS = dir ? FT1 : FT0;
  const char* FO = dir ? FT0 : FT1;
  const int* idx = dir ? i10 : i01;
  const float* ssd = ss + dir * 128;
  float* dout = dir ? DF1 : DF0;
  __shared__ __align__(16) unsigned WlU[64 * 36];
  __shared__ __align__(16) unsigned HtU[64 * 36];
  __shared__ unsigned Gs[4][32];
  __shared__ int idxt[64];
  __shared__ float sc[64], sh[64], bb[64];
  int t = threadIdx.x;
  int r = t >> 2, q = t & 3;
  {
    const float4* w4 = (const float4*)(w2d + r * 64 + q * 16);
#pragma unroll
    for (int uu = 0; uu < 4; uu++) {
      float4 v = w4[uu];
      WlU[r * 36 + q * 8 + uu * 2] = pack_bf16x2(v.x, v.y);
      WlU[r * 36 + q * 8 + uu * 2 + 1] = pack_bf16x2(v.z, v.w);
    }
  }
  if (t < 64) {
    sc[t] = ssd[t];
    sh[t] = ssd[64 + t];
    bb[t] = b2d[t];
  }
  int wave = t >> 6, lane = t & 63;
  int lr = lane & 15, lg = lane >> 4;
  int p = r >> 4;
  int wblk = blockIdx.x >> 3;  // 0..511
  int bbase = batch * Nn;
#pragma unroll
  for (int tt = 0; tt < 4; tt++) {
    int tile = wblk * 4 + tt;          // 0..2047 within batch
    int ptb = batch * Nn + tile * 4;
    __syncthreads();
    if (t < 64) idxt[t] = idx[ptb * 16 + t];
    if (t < 128)
      Gs[t >> 5][t & 31] =
          *(const unsigned*)(FS + (size_t)(ptb + (t >> 5)) * FT_STRIDE + 256 + (t & 31) * 4);
    __syncthreads();
    const char* orow = FO + (size_t)(bbase + idxt[r]) * FT_STRIDE + 256;
    uint4 g0 = *(const uint4*)(orow + q * 32);
    uint4 g1 = *(const uint4*)(orow + q * 32 + 16);
#pragma unroll
    for (int uu = 0; uu < 8; uu++) {
      unsigned gdo2 = (uu < 4) ? ((const unsigned*)&g0)[uu] : ((const unsigned*)&g1)[uu - 4];
      unsigned gds2 = Gs[p][q * 8 + uu];
      int c = q * 16 + uu * 2;
      float h0 = fmaxf(sc[c] * (bf16_lo(gds2) - bf16_lo(gdo2)) + sh[c], 0.f);
      float h1 = fmaxf(sc[c + 1] * (bf16_hi(gds2) - bf16_hi(gdo2)) + sh[c + 1], 0.f);
      HtU[r * 36 + q * 8 + uu] = pack_bf16x2(h0, h1);
    }
    __syncthreads();
    v4f acc[4] = {{0, 0, 0, 0}, {0, 0, 0, 0}, {0, 0, 0, 0}, {0, 0, 0, 0}};
    v8bf a0 = *(const v8bf*)&HtU[(wave * 16 + lr) * 36 + lg * 4];
    v8bf a1 = *(const v8bf*)&HtU[(wave * 16 + lr) * 36 + 16 + lg * 4];
#pragma unroll
    for (int c = 0; c < 4; c++) {
      v8bf b0 = *(const v8bf*)&WlU[(c * 16 + lr) * 36 + lg * 4];
      v8bf b1 = *(const v8bf*)&WlU[(c * 16 + lr) * 36 + 16 + lg * 4];
      acc[c] = __builtin_amdgcn_mfma_f32_16x16x32_bf16(a0, b0, acc[c], 0, 0, 0);
      acc[c] = __builtin_amdgcn_mfma_f32_16x16x32_bf16(a1, b1, acc[c], 0, 0, 0);
    }
#pragma unroll
    for (int c = 0; c < 4; c++) {
      float mm = fmaxf(fmaxf(acc[c][0], acc[c][1]), fmaxf(acc[c][2], acc[c][3]));
      mm = fmaxf(mm, __shfl_xor(mm, 16));
      mm = fmaxf(mm, __shfl_xor(mm, 32));
      if (lane < 16) dout[(size_t)(ptb + wave) * 64 + c * 16 + lane] = mm + bb[c * 16 + lane];
    }
  }
}

// ---------------- SF = relu(bn(YS)) @ sw2^T + sb2 ----------------
__global__ __launch_bounds__(256) void simfeat_gemm(
    const float* __restrict__ YS0, const float* __restrict__ YS1,
    const float* __restrict__ ss, const float* __restrict__ sw2,
    const float* __restrict__ sb2, float* __restrict__ SF0, float* __restrict__ SF1) {
  int dir = blockIdx.y;
  const float* ysim = dir ? YS1 : YS0;
  const float* ssS = ss + 256 + dir * 128;
  float* sf = dir ? SF1 : SF0;
  __shared__ float Wl[64][65];
  __shared__ float Hl[64][65];
  __shared__ float sc[64], sh[64], bb[64];
  int t = threadIdx.x;
  if (t < 64) {
    sc[t] = ssS[t];
    sh[t] = ssS[64 + t];
    bb[t] = sb2[t];
  }
#pragma unroll
  for (int i = 0; i < 16; i++) {
    int ix = t + i * 256;
    Wl[ix >> 6][ix & 63] = sw2[ix];
  }
  __syncthreads();
  int ptb = blockIdx.x * 64;
#pragma unroll
  for (int i = 0; i < 16; i++) {
    int ix = t + i * 256;
    int row = ix >> 6, col = ix & 63;
    float v = ysim[(size_t)ptb * 64 + ix];
    Hl[row][col] = fmaxf(sc[col] * v + sh[col], 0.f);
  }
  __syncthreads();
  int ty = t >> 4, tx = t & 15, r0 = ty * 4, c0 = tx * 4;
  float acc[4][4] = {};
#pragma unroll 4
  for (int j = 0; j < 64; ++j) {
    float a[4], w[4];
#pragma unroll
    for (int i = 0; i < 4; i++) a[i] = Hl[r0 + i][j];
#pragma unroll
    for (int m = 0; m < 4; m++) w[m] = Wl[c0 + m][j];
#pragma unroll
    for (int i = 0; i < 4; i++)
#pragma unroll
      for (int m = 0; m < 4; m++) acc[i][m] += a[i] * w[m];
  }
#pragma unroll
  for (int i = 0; i < 4; i++) {
    float4 v = make_float4(acc[i][0] + bb[c0], acc[i][1] + bb[c0 + 1],
                           acc[i][2] + bb[c0 + 2], acc[i][3] + bb[c0 + 3]);
    *reinterpret_cast<float4*>(sf + (size_t)(ptb + r0 + i) * 64 + c0) = v;
  }
}

// ---------------- YF = [DF|SF] @ fw1^T + fin BN stats ----------------
__global__ __launch_bounds__(256) void yfin_gemm(
    const float* __restrict__ DF0, const float* __restrict__ DF1,
    const float* __restrict__ SF0, const float* __restrict__ SF1,
    const float* __restrict__ fw1, float* __restrict__ YF0, float* __restrict__ YF1,
    float* __restrict__ acc) {
  int dir = blockIdx.z;
  const float* df = dir ? DF1 : DF0;
  const float* sf = dir ? SF1 : SF0;
  float* yf = dir ? YF1 : YF0;
  float* accF = acc + 512 + dir * 256;
  __shared__ float Wl[64][129];
  __shared__ float Cl[64][65];
  __shared__ float redS[64], redQ[64];
  int t = threadIdx.x;
  int y = blockIdx.y;
  if (t < 64) {
    redS[t] = 0.f;
    redQ[t] = 0.f;
  }
#pragma unroll
  for (int i = 0; i < 32; i++) {
    int ix = t + i * 256;
    Wl[ix >> 7][ix & 127] = fw1[(size_t)(y * 64 + (ix >> 7)) * 128 + (ix & 127)];
  }
  int ptb = blockIdx.x * 64;
#pragma unroll
  for (int i = 0; i < 16; i++) {
    int ix = t + i * 256;
    Cl[ix >> 6][ix & 63] = df[(size_t)ptb * 64 + ix];
  }
  __syncthreads();
  int ty = t >> 4, tx = t & 15, r0 = ty * 4, c0 = tx * 4;
  float acc4[4][4] = {};
#pragma unroll 4
  for (int j = 0; j < 64; ++j) {
    float a[4], w[4];
#pragma unroll
    for (int i = 0; i < 4; i++) a[i] = Cl[r0 + i][j];
#pragma unroll
    for (int m = 0; m < 4; m++) w[m] = Wl[c0 + m][j];
#pragma unroll
    for (int i = 0; i < 4; i++)
#pragma unroll
      for (int m = 0; m < 4; m++) acc4[i][m] += a[i] * w[m];
  }
  __syncthreads();
#pragma unroll
  for (int i = 0; i < 16; i++) {
    int ix = t + i * 256;
    Cl[ix >> 6][ix & 63] = sf[(size_t)ptb * 64 + ix];
  }
  __syncthreads();
#pragma unroll 4
  for (int j = 0; j < 64; ++j) {
    float a[4], w[4];
#pragma unroll
    for (int i = 0; i < 4; i++) a[i] = Cl[r0 + i][j];
#pragma unroll
    for (int m = 0; m < 4; m++) w[m] = Wl[c0 + m][64 + j];
#pragma unroll
    for (int i = 0; i < 4; i++)
#pragma unroll
      for (int m = 0; m < 4; m++) acc4[i][m] += a[i] * w[m];
  }
#pragma unroll
  for (int i = 0; i < 4; i++) {
    float4 v = make_float4(acc4[i][0], acc4[i][1], acc4[i][2], acc4[i][3]);
    *reinterpret_cast<float4*>(yf + (size_t)(ptb + r0 + i) * 128 + y * 64 + c0) = v;
  }
#pragma unroll
  for (int m = 0; m < 4; m++) {
    float s = acc4[0][m] + acc4[1][m] + acc4[2][m] + acc4[3][m];
    float qq = acc4[0][m] * acc4[0][m] + acc4[1][m] * acc4[1][m] +
               acc4[2][m] * acc4[2][m] + acc4[3][m] * acc4[3][m];
    atomicAdd(&redS[c0 + m], s);
    atomicAdd(&redQ[c0 + m], qq);
  }
  __syncthreads();
  if (t < 64) {
    atomicAdd(accF + y * 64 + t, redS[t]);
    atomicAdd(accF + 128 + y * 64 + t, redQ[t]);
  }
}

// ---------------- finalize fin0, fin1 ----------------
__global__ void finalize2(const float* __restrict__ accF, const float* __restrict__ fg,
                          const float* __restrict__ fbeta, float* __restrict__ ssF) {
  int t = threadIdx.x;
  int seg = t >> 7, c = t & 127;
  const float* a = accF + seg * 256;
  float mu = a[c] / (float)NPTS;
  float var = a[128 + c] / (float)NPTS - mu * mu;
  float scale = fg[c] * rsqrtf(var + EPSf);
  ssF[seg * 256 + c] = scale;
  ssF[seg * 256 + 128 + c] = fbeta[c] - mu * scale;
}

// ---------------- out = relu(bn(YF)) @ fw2^T + fb2 ----------------
__global__ __launch_bounds__(256) void finout_gemm(
    const float* __restrict__ YF0, const float* __restrict__ YF1,
    const float* __restrict__ ss, const float* __restrict__ fw2,
    const float* __restrict__ fb2, float* __restrict__ out) {
  int dir = blockIdx.y;
  const float* yf = dir ? YF1 : YF0;
  const float* ssF = ss + 512 + dir * 256;
  float* outp = out + (size_t)dir * NPTS * 64;
  __shared__ float Wl[64][129];
  __shared__ float Hl[64][65];
  __shared__ float scl[128], shf[128], bb[64];
  int t = threadIdx.x;
  if (t < 128) {
    scl[t] = ssF[t];
    shf[t] = ssF[128 + t];
  }
  if (t < 64) bb[t] = fb2[t];
#pragma unroll
  for (int i = 0; i < 32; i++) {
    int ix = t + i * 256;
    Wl[ix >> 7][ix & 127] = fw2[ix];
  }
  __syncthreads();
  int ptb = blockIdx.x * 64;
  int ty = t >> 4, tx = t & 15, r0 = ty * 4, c0 = tx * 4;
  float acc[4][4] = {};
#pragma unroll
  for (int i = 0; i < 16; i++) {
    int ix = t + i * 256;
    int row = ix >> 6, jj = ix & 63;
    float v = yf[(size_t)(ptb + row) * 128 + jj];
    Hl[row][jj] = fmaxf(scl[jj] * v + shf[jj], 0.f);
  }
  __syncthreads();
#pragma unroll 4
  for (int j = 0; j < 64; ++j) {
    float a[4], w[4];
#pragma unroll
    for (int i = 0; i < 4; i++) a[i] = Hl[r0 + i][j];
#pragma unroll
    for (int m = 0; m < 4; m++) w[m] = Wl[c0 + m][j];
#pragma unroll
    for (int i = 0; i < 4; i++)
#pragma unroll
      for (int m = 0; m < 4; m++) acc[i][m] += a[i] * w[m];
  }
  __syncthreads();
#pragma unroll
  for (int i = 0; i < 16; i++) {
    int ix = t + i * 256;
    int row = ix >> 6, jj = ix & 63;
    float v = yf[(size_t)(ptb + row) * 128 + 64 + jj];
    Hl[row][jj] = fmaxf(scl[64 + jj] * v + shf[64 + jj], 0.f);
  }
  __syncthreads();
#pragma unroll 4
  for (int j = 0; j < 64; ++j) {
    float a[4], w[4];
#pragma unroll
    for (int i = 0; i < 4; i++) a[i] = Hl[r0 + i][j];
#pragma unroll
    for (int m = 0; m < 4; m++) w[m] = Wl[c0 + m][64 + j];
#pragma unroll
    for (int i = 0; i < 4; i++)
#pragma unroll
      for (int m = 0; m < 4; m++) acc[i][m] += a[i] * w[m];
  }
#pragma unroll
  for (int i = 0; i < 4; i++) {
    float4 v = make_float4(acc[i][0] + bb[c0], acc[i][1] + bb[c0 + 1],
                           acc[i][2] + bb[c0 + 2], acc[i][3] + bb[c0 + 3]);
    *reinterpret_cast<float4*>(outp + (size_t)(ptb + r0 + i) * 64 + c0) = v;
  }
}

extern "C" void kernel_launch(void* const* d_in, const int* in_sizes, int n_in,
                              void* d_out, int out_size, void* d_ws, size_t ws_size,
                              hipStream_t stream) {
  const float* f0 = (const float*)d_in[0];
  const float* f1 = (const float*)d_in[1];
  const int* i01 = (const int*)d_in[2];
  const int* i10 = (const int*)d_in[3];
  const float* dw1 = (const float*)d_in[4];
  const float* dg = (const float*)d_in[6];
  const float* dbe = (const float*)d_in[7];
  const float* dw2 = (const float*)d_in[8];
  const float* db2 = (const float*)d_in[9];
  const float* sw1 = (const float*)d_in[10];
  const float* sg = (const float*)d_in[12];
  const float* sbe = (const float*)d_in[13];
  const float* sw2 = (const float*)d_in[14];
  const float* sb2 = (const float*)d_in[15];
  const float* fw1 = (const float*)d_in[16];
  const float* fg = (const float*)d_in[18];
  const float* fbe = (const float*)d_in[19];
  const float* fw2 = (const float*)d_in[20];
  const float* fb2 = (const float*)d_in[21];

  char* wsb = (char*)d_ws;
  float* out = (float*)d_out;

  char* FT0 = wsb;                            // 16 MB (32768*512)
  char* FT1 = wsb + (size_t)NPTS * FT_STRIDE; // 16 MB
  float* acc = (float*)(wsb + 2 * (size_t)NPTS * FT_STRIDE);  // @32MB
  float* ss = acc + 2048;
  float* YS0 = (float*)(wsb + 2 * (size_t)NPTS * FT_STRIDE + 65536);
  float* YS1 = YS0 + GSZ;
  float* DF0 = YS1 + GSZ;
  float* DF1 = DF0 + GSZ;
  float* SF0 = DF1 + GSZ;
  float* SF1 = SF0 + GSZ;
  float* YF0 = YS0;         // 16MB over YS0+YS1 (dead after simfeat_gemm)
  float* YF1 = (float*)FT0; // 16MB over FT0 (dead after diff_out_k)

  hipMemsetAsync(acc, 0, 1024 * sizeof(float), stream);
  gemmG<<<dim3(512, 1, 2), 256, 0, stream>>>(f0, f1, dw1, sw1, FT0, FT1);

  stats_sim<<<4096, 256, 0, stream>>>(FT0, FT1, i01, i10, YS0, YS1, acc);

  finalize1<<<1, 256, 0, stream>>>(acc, dg, dbe, sg, sbe, ss);

  diff_out_k<<<4096, 256, 0, stream>>>(FT0, FT1, i01, i10, dw2, db2, ss, DF0, DF1);

  simfeat_gemm<<<dim3(512, 2), 256, 0, stream>>>(YS0, YS1, ss, sw2, sb2, SF0, SF1);

  yfin_gemm<<<dim3(512, 2, 2), 256, 0, stream>>>(DF0, DF1, SF0, SF1, fw1, YF0, YF1, acc);

  finalize2<<<1, 256, 0, stream>>>(acc + 512, fg, fbe, ss + 512);

  finout_gemm<<<dim3(512, 2), 256, 0, stream>>>(YF0, YF1, ss, fw2, fb2, out);
}

// Round 12
// 263.385 us; speedup vs baseline: 1.3632x; 1.3632x over previous
//
#include <hip/hip_runtime.h>

// PointSetDifferenceModule: B=4, N=8192, C=64, K=16
// Round 12: r11's XCD-affinity gather mapping + unroll-1 point loop in stats_sim
// (r11's full unroll blew VGPR 60->156, occupancy 32%->11%).
// FT row (512B): [ f fp32 x64 | G_d bf16 x64 | G_s bf16 x64 ]

#define Bn 4
#define Nn 8192
#define NPTS (Bn * Nn)        // 32768
#define NSAMP (NPTS * 16)     // 524288
#define EPSf 1e-5f
#define FT_STRIDE 512
#define GSZ (NPTS * 64)

typedef __attribute__((ext_vector_type(8))) short v8bf;
typedef __attribute__((ext_vector_type(4))) float v4f;

__device__ inline unsigned pack_bf16x2(float a, float b) {
  unsigned ua = __float_as_uint(a), ub = __float_as_uint(b);
  ua = (ua + 0x7FFFu + ((ua >> 16) & 1u)) >> 16;
  ub = (ub + 0x7FFFu + ((ub >> 16) & 1u)) >> 16;
  return (ub << 16) | ua;
}
__device__ inline float bf16_lo(unsigned u) { return __uint_as_float(u << 16); }
__device__ inline float bf16_hi(unsigned u) { return __uint_as_float(u & 0xFFFF0000u); }

// ---------------- build fused tables: f fp32 + G_d, G_s bf16 ----------------
__global__ __launch_bounds__(256) void gemmG(const float* __restrict__ f0,
                                             const float* __restrict__ f1,
                                             const float* __restrict__ wd,
                                             const float* __restrict__ wsim,
                                             char* __restrict__ FT0,
                                             char* __restrict__ FT1) {
  int z = blockIdx.z;
  const float* F = z ? f1 : f0;
  char* FT = z ? FT1 : FT0;
  __shared__ float Fl[64][65];
  __shared__ float Wd[64][65];
  __shared__ float Ws[64][65];
  int t = threadIdx.x;
#pragma unroll
  for (int i = 0; i < 16; i++) {
    int ix = t + i * 256;
    Wd[ix >> 6][ix & 63] = wd[ix];
    Ws[ix >> 6][ix & 63] = wsim[ix];
  }
  int ptb = blockIdx.x * 64;
#pragma unroll
  for (int i = 0; i < 16; i++) {
    int ix = t + i * 256;
    float v = F[(size_t)ptb * 64 + ix];
    Fl[ix >> 6][ix & 63] = v;
    *(float*)(FT + (size_t)(ptb + (ix >> 6)) * FT_STRIDE + (ix & 63) * 4) = v;
  }
  __syncthreads();
  int ty = t >> 4, tx = t & 15, r0 = ty * 4, c0 = tx * 4;
  float ad[4][4] = {}, as_[4][4] = {};
#pragma unroll 4
  for (int j = 0; j < 64; ++j) {
    float a[4], w1[4], w2[4];
#pragma unroll
    for (int i = 0; i < 4; i++) a[i] = Fl[r0 + i][j];
#pragma unroll
    for (int m = 0; m < 4; m++) {
      w1[m] = Wd[c0 + m][j];
      w2[m] = Ws[c0 + m][j];
    }
#pragma unroll
    for (int i = 0; i < 4; i++)
#pragma unroll
      for (int m = 0; m < 4; m++) {
        ad[i][m] += a[i] * w1[m];
        as_[i][m] += a[i] * w2[m];
      }
  }
#pragma unroll
  for (int i = 0; i < 4; i++) {
    char* row = FT + (size_t)(ptb + r0 + i) * FT_STRIDE;
    uint2 gd2 = make_uint2(pack_bf16x2(ad[i][0], ad[i][1]),
                           pack_bf16x2(ad[i][2], ad[i][3]));
    *(uint2*)(row + 256 + c0 * 2) = gd2;
    uint2 gs2 = make_uint2(pack_bf16x2(as_[i][0], as_[i][1]),
                           pack_bf16x2(as_[i][2], as_[i][3]));
    *(uint2*)(row + 384 + c0 * 2) = gs2;
  }
}

// ---------------- diff stats + sim softmax + y_sim (one wave per point) ----------------
// lane 0-31: f pairs | lane 32-47: gd x4 | lane 48-63: gs x4
// XCD affinity: unit = blockIdx.x & 7 -> (dir, batch).
__global__ __launch_bounds__(256) void stats_sim(
    const char* __restrict__ FT0, const char* __restrict__ FT1,
    const int* __restrict__ i01, const int* __restrict__ i10,
    float* __restrict__ YS0, float* __restrict__ YS1, float* __restrict__ acc) {
  int u = blockIdx.x & 7;
  int dir = u & 1, batch = u >> 1;
  const char* FS = dir ? FT1 : FT0;
  const char* FO = dir ? FT0 : FT1;
  const int* idx = dir ? i10 : i01;
  float* ys = dir ? YS1 : YS0;
  float* accDiff = acc + dir * 128;
  float* accSim = acc + 256 + dir * 128;
  int lane = threadIdx.x & 63, wave = threadIdx.x >> 6;
  int w = blockIdx.x >> 3;              // 0..511
  int gw = w * 4 + wave;                // 0..2047
  int ptbase = batch * Nn + gw * 4;     // 4 consecutive points per wave
  int bbase = batch * Nn;
  bool isD = (lane >= 32) && (lane < 48);
  bool isS = lane >= 48;
  int lq = lane & 15;
  float sdl[4] = {0, 0, 0, 0}, qdl[4] = {0, 0, 0, 0};
  float ssl[4] = {0, 0, 0, 0}, qsl[4] = {0, 0, 0, 0};
#pragma unroll 1
  for (int pi = 0; pi < 4; pi++) {
    int ptu = ptbase + pi;  // wave-uniform
    const char* srow = FS + (size_t)ptu * FT_STRIDE;
    uint2 selfr = *(const uint2*)(srow + lane * 8);
    const int* ip = idx + ptu * 16;
    int jx[16];
#pragma unroll
    for (int k = 0; k < 16; k++) jx[k] = ip[k];
    const char* ob = FO + (size_t)bbase * FT_STRIDE;
    uint2 nb[16];
#pragma unroll
    for (int k = 0; k < 16; k++)
      nb[k] = *(const uint2*)(ob + (size_t)jx[k] * FT_STRIDE + lane * 8);
    float fsx = __uint_as_float(selfr.x), fsy = __uint_as_float(selfr.y);
    float gds0 = bf16_lo(selfr.x), gds1 = bf16_hi(selfr.x);
    float gds2 = bf16_lo(selfr.y), gds3 = bf16_hi(selfr.y);
    float sims[16];
#pragma unroll
    for (int k = 0; k < 16; k++) {
      float p = fsx * __uint_as_float(nb[k].x) + fsy * __uint_as_float(nb[k].y);
      p += __shfl_xor(p, 16);
      p += __shfl_xor(p, 8);
      p += __shfl_xor(p, 4);
      p += __shfl_xor(p, 2);
      p += __shfl_xor(p, 1);
      sims[k] = __uint_as_float(__builtin_amdgcn_readfirstlane(__float_as_uint(p)));
      // unguarded accumulation: only lanes 32-47's values are ever read
      float y0 = gds0 - bf16_lo(nb[k].x);
      float y1 = gds1 - bf16_hi(nb[k].x);
      float y2 = gds2 - bf16_lo(nb[k].y);
      float y3 = gds3 - bf16_hi(nb[k].y);
      sdl[0] += y0; qdl[0] += y0 * y0;
      sdl[1] += y1; qdl[1] += y1 * y1;
      sdl[2] += y2; qdl[2] += y2 * y2;
      sdl[3] += y3; qdl[3] += y3 * y3;
    }
    float mmax = sims[0];
#pragma unroll
    for (int k = 1; k < 16; k++) mmax = fmaxf(mmax, sims[k]);
    float den = 0.f, ya0 = 0.f, ya1 = 0.f, ya2 = 0.f, ya3 = 0.f;
#pragma unroll
    for (int k = 0; k < 16; k++) {
      float e = __expf(sims[k] - mmax);
      den += e;
      ya0 += e * bf16_lo(nb[k].x);
      ya1 += e * bf16_hi(nb[k].x);
      ya2 += e * bf16_lo(nb[k].y);
      ya3 += e * bf16_hi(nb[k].y);
    }
    float inv = 1.f / den;
    ya0 *= inv; ya1 *= inv; ya2 *= inv; ya3 *= inv;
    if (isS)
      *(float4*)(ys + (size_t)ptu * 64 + lq * 4) = make_float4(ya0, ya1, ya2, ya3);
    ssl[0] += ya0; qsl[0] += ya0 * ya0;
    ssl[1] += ya1; qsl[1] += ya1 * ya1;
    ssl[2] += ya2; qsl[2] += ya2 * ya2;
    ssl[3] += ya3; qsl[3] += ya3 * ya3;
  }
  __shared__ float rA[4][64], rB[4][64], rC[4][64], rD2[4][64];
  int cd = lq * 4;
  if (isD) {
#pragma unroll
    for (int i = 0; i < 4; i++) {
      rA[wave][cd + i] = sdl[i];
      rB[wave][cd + i] = qdl[i];
    }
  }
  if (isS) {
#pragma unroll
    for (int i = 0; i < 4; i++) {
      rC[wave][cd + i] = ssl[i];
      rD2[wave][cd + i] = qsl[i];
    }
  }
  __syncthreads();
  if (wave == 0) {
    float v = rA[0][lane] + rA[1][lane] + rA[2][lane] + rA[3][lane];
    atomicAdd(accDiff + lane, v);
    v = rB[0][lane] + rB[1][lane] + rB[2][lane] + rB[3][lane];
    atomicAdd(accDiff + 64 + lane, v);
    v = rC[0][lane] + rC[1][lane] + rC[2][lane] + rC[3][lane];
    atomicAdd(accSim + lane, v);
    v = rD2[0][lane] + rD2[1][lane] + rD2[2][lane] + rD2[3][lane];
    atomicAdd(accSim + 64 + lane, v);
  }
}

// ---------------- finalize diff0,diff1,sim0,sim1 ----------------
__global__ void finalize1(const float* __restrict__ acc, const float* __restrict__ dg,
                          const float* __restrict__ dbeta, const float* __restrict__ sg,
                          const float* __restrict__ sbeta, float* __restrict__ ss) {
  int t = threadIdx.x;
  int seg = t >> 6, c = t & 63;
  const float* a = acc + seg * 128;
  float cnt = (seg < 2) ? (float)NSAMP : (float)NPTS;
  float mu = a[c] / cnt;
  float var = a[64 + c] / cnt - mu * mu;
  const float* g = (seg < 2) ? dg : sg;
  const float* be = (seg < 2) ? dbeta : sbeta;
  float scale = g[c] * rsqrtf(var + EPSf);
  ss[seg * 128 + c] = scale;
  ss[seg * 128 + 64 + c] = be[c] - mu * scale;
}

// ---------------- diff output: gather bf16 + BN/relu + MFMA GEMM + max over K --------
// Same XCD-affinity mapping: unit = blockIdx.x & 7 -> (dir,batch); 4 tiles/block.
__global__ __launch_bounds__(256) void diff_out_k(
    const char* __restrict__ FT0, const char* __restrict__ FT1,
    const int* __restrict__ i01, const int* __restrict__ i10,
    const float* __restrict__ w2d, const float* __restrict__ b2d,
    const float* __restrict__ ss, float* __restrict__ DF0, float* __restrict__ DF1) {
  int u = blockIdx.x & 7;
  int dir = u & 1, batch = u >> 1;
  const char* FS = dir ? FT1 : FT0;
  const char* FO = dir ? FT0 : FT1;
  const int* idx = dir ? i10 : i01;
  const float* ssd = ss + dir * 128;
  float* dout = dir ? DF1 : DF0;
  __shared__ __align__(16) unsigned WlU[64 * 36];
  __shared__ __align__(16) unsigned HtU[64 * 36];
  __shared__ unsigned Gs[4][32];
  __shared__ int idxt[64];
  __shared__ float sc[64], sh[64], bb[64];
  int t = threadIdx.x;
  int r = t >> 2, q = t & 3;
  {
    const float4* w4 = (const float4*)(w2d + r * 64 + q * 16);
#pragma unroll
    for (int uu = 0; uu < 4; uu++) {
      float4 v = w4[uu];
      WlU[r * 36 + q * 8 + uu * 2] = pack_bf16x2(v.x, v.y);
      WlU[r * 36 + q * 8 + uu * 2 + 1] = pack_bf16x2(v.z, v.w);
    }
  }
  if (t < 64) {
    sc[t] = ssd[t];
    sh[t] = ssd[64 + t];
    bb[t] = b2d[t];
  }
  int wave = t >> 6, lane = t & 63;
  int lr = lane & 15, lg = lane >> 4;
  int p = r >> 4;
  int wblk = blockIdx.x >> 3;  // 0..511
  int bbase = batch * Nn;
#pragma unroll 1
  for (int tt = 0; tt < 4; tt++) {
    int tile = wblk * 4 + tt;          // 0..2047 within batch
    int ptb = batch * Nn + tile * 4;
    __syncthreads();
    if (t < 64) idxt[t] = idx[ptb * 16 + t];
    if (t < 128)
      Gs[t >> 5][t & 31] =
          *(const unsigned*)(FS + (size_t)(ptb + (t >> 5)) * FT_STRIDE + 256 + (t & 31) * 4);
    __syncthreads();
    const char* orow = FO + (size_t)(bbase + idxt[r]) * FT_STRIDE + 256;
    uint4 g0 = *(const uint4*)(orow + q * 32);
    uint4 g1 = *(const uint4*)(orow + q * 32 + 16);
#pragma unroll
    for (int uu = 0; uu < 8; uu++) {
      unsigned gdo2 = (uu < 4) ? ((const unsigned*)&g0)[uu] : ((const unsigned*)&g1)[uu - 4];
      unsigned gds2 = Gs[p][q * 8 + uu];
      int c = q * 16 + uu * 2;
      float h0 = fmaxf(sc[c] * (bf16_lo(gds2) - bf16_lo(gdo2)) + sh[c], 0.f);
      float h1 = fmaxf(sc[c + 1] * (bf16_hi(gds2) - bf16_hi(gdo2)) + sh[c + 1], 0.f);
      HtU[r * 36 + q * 8 + uu] = pack_bf16x2(h0, h1);
    }
    __syncthreads();
    v4f acc[4] = {{0, 0, 0, 0}, {0, 0, 0, 0}, {0, 0, 0, 0}, {0, 0, 0, 0}};
    v8bf a0 = *(const v8bf*)&HtU[(wave * 16 + lr) * 36 + lg * 4];
    v8bf a1 = *(const v8bf*)&HtU[(wave * 16 + lr) * 36 + 16 + lg * 4];
#pragma unroll
    for (int c = 0; c < 4; c++) {
      v8bf b0 = *(const v8bf*)&WlU[(c * 16 + lr) * 36 + lg * 4];
      v8bf b1 = *(const v8bf*)&WlU[(c * 16 + lr) * 36 + 16 + lg * 4];
      acc[c] = __builtin_amdgcn_mfma_f32_16x16x32_bf16(a0, b0, acc[c], 0, 0, 0);
      acc[c] = __builtin_amdgcn_mfma_f32_16x16x32_bf16(a1, b1, acc[c], 0, 0, 0);
    }
#pragma unroll
    for (int c = 0; c < 4; c++) {
      float mm = fmaxf(fmaxf(acc[c][0], acc[c][1]), fmaxf(acc[c][2], acc[c][3]));
      mm = fmaxf(mm, __shfl_xor(mm, 16));
      mm = fmaxf(mm, __shfl_xor(mm, 32));
      if (lane < 16) dout[(size_t)(ptb + wave) * 64 + c * 16 + lane] = mm + bb[c * 16 + lane];
    }
  }
}

// ---------------- SF = relu(bn(YS)) @ sw2^T + sb2 ----------------
__global__ __launch_bounds__(256) void simfeat_gemm(
    const float* __restrict__ YS0, const float* __restrict__ YS1,
    const float* __restrict__ ss, const float* __restrict__ sw2,
    const float* __restrict__ sb2, float* __restrict__ SF0, float* __restrict__ SF1) {
  int dir = blockIdx.y;
  const float* ysim = dir ? YS1 : YS0;
  const float* ssS = ss + 256 + dir * 128;
  float* sf = dir ? SF1 : SF0;
  __shared__ float Wl[64][65];
  __shared__ float Hl[64][65];
  __shared__ float sc[64], sh[64], bb[64];
  int t = threadIdx.x;
  if (t < 64) {
    sc[t] = ssS[t];
    sh[t] = ssS[64 + t];
    bb[t] = sb2[t];
  }
#pragma unroll
  for (int i = 0; i < 16; i++) {
    int ix = t + i * 256;
    Wl[ix >> 6][ix & 63] = sw2[ix];
  }
  __syncthreads();
  int ptb = blockIdx.x * 64;
#pragma unroll
  for (int i = 0; i < 16; i++) {
    int ix = t + i * 256;
    int row = ix >> 6, col = ix & 63;
    float v = ysim[(size_t)ptb * 64 + ix];
    Hl[row][col] = fmaxf(sc[col] * v + sh[col], 0.f);
  }
  __syncthreads();
  int ty = t >> 4, tx = t & 15, r0 = ty * 4, c0 = tx * 4;
  float acc[4][4] = {};
#pragma unroll 4
  for (int j = 0; j < 64; ++j) {
    float a[4], w[4];
#pragma unroll
    for (int i = 0; i < 4; i++) a[i] = Hl[r0 + i][j];
#pragma unroll
    for (int m = 0; m < 4; m++) w[m] = Wl[c0 + m][j];
#pragma unroll
    for (int i = 0; i < 4; i++)
#pragma unroll
      for (int m = 0; m < 4; m++) acc[i][m] += a[i] * w[m];
  }
#pragma unroll
  for (int i = 0; i < 4; i++) {
    float4 v = make_float4(acc[i][0] + bb[c0], acc[i][1] + bb[c0 + 1],
                           acc[i][2] + bb[c0 + 2], acc[i][3] + bb[c0 + 3]);
    *reinterpret_cast<float4*>(sf + (size_t)(ptb + r0 + i) * 64 + c0) = v;
  }
}

// ---------------- YF = [DF|SF] @ fw1^T + fin BN stats ----------------
__global__ __launch_bounds__(256) void yfin_gemm(
    const float* __restrict__ DF0, const float* __restrict__ DF1,
    const float* __restrict__ SF0, const float* __restrict__ SF1,
    const float* __restrict__ fw1, float* __restrict__ YF0, float* __restrict__ YF1,
    float* __restrict__ acc) {
  int dir = blockIdx.z;
  const float* df = dir ? DF1 : DF0;
  const float* sf = dir ? SF1 : SF0;
  float* yf = dir ? YF1 : YF0;
  float* accF = acc + 512 + dir * 256;
  __shared__ float Wl[64][129];
  __shared__ float Cl[64][65];
  __shared__ float redS[64], redQ[64];
  int t = threadIdx.x;
  int y = blockIdx.y;
  if (t < 64) {
    redS[t] = 0.f;
    redQ[t] = 0.f;
  }
#pragma unroll
  for (int i = 0; i < 32; i++) {
    int ix = t + i * 256;
    Wl[ix >> 7][ix & 127] = fw1[(size_t)(y * 64 + (ix >> 7)) * 128 + (ix & 127)];
  }
  int ptb = blockIdx.x * 64;
#pragma unroll
  for (int i = 0; i < 16; i++) {
    int ix = t + i * 256;
    Cl[ix >> 6][ix & 63] = df[(size_t)ptb * 64 + ix];
  }
  __syncthreads();
  int ty = t >> 4, tx = t & 15, r0 = ty * 4, c0 = tx * 4;
  float acc4[4][4] = {};
#pragma unroll 4
  for (int j = 0; j < 64; ++j) {
    float a[4], w[4];
#pragma unroll
    for (int i = 0; i < 4; i++) a[i] = Cl[r0 + i][j];
#pragma unroll
    for (int m = 0; m < 4; m++) w[m] = Wl[c0 + m][j];
#pragma unroll
    for (int i = 0; i < 4; i++)
#pragma unroll
      for (int m = 0; m < 4; m++) acc4[i][m] += a[i] * w[m];
  }
  __syncthreads();
#pragma unroll
  for (int i = 0; i < 16; i++) {
    int ix = t + i * 256;
    Cl[ix >> 6][ix & 63] = sf[(size_t)ptb * 64 + ix];
  }
  __syncthreads();
#pragma unroll 4
  for (int j = 0; j < 64; ++j) {
    float a[4], w[4];
#pragma unroll
    for (int i = 0; i < 4; i++) a[i] = Cl[r0 + i][j];
#pragma unroll
    for (int m = 0; m < 4; m++) w[m] = Wl[c0 + m][64 + j];
#pragma unroll
    for (int i = 0; i < 4; i++)
#pragma unroll
      for (int m = 0; m < 4; m++) acc4[i][m] += a[i] * w[m];
  }
#pragma unroll
  for (int i = 0; i < 4; i++) {
    float4 v = make_float4(acc4[i][0], acc4[i][1], acc4[i][2], acc4[i][3]);
    *reinterpret_cast<float4*>(yf + (size_t)(ptb + r0 + i) * 128 + y * 64 + c0) = v;
  }
#pragma unroll
  for (int m = 0; m < 4; m++) {
    float s = acc4[0][m] + acc4[1][m] + acc4[2][m] + acc4[3][m];
    float qq = acc4[0][m] * acc4[0][m] + acc4[1][m] * acc4[1][m] +
               acc4[2][m] * acc4[2][m] + acc4[3][m] * acc4[3][m];
    atomicAdd(&redS[c0 + m], s);
    atomicAdd(&redQ[c0 + m], qq);
  }
  __syncthreads();
  if (t < 64) {
    atomicAdd(accF + y * 64 + t, redS[t]);
    atomicAdd(accF + 128 + y * 64 + t, redQ[t]);
  }
}

// ---------------- finalize fin0, fin1 ----------------
__global__ void finalize2(const float* __restrict__ accF, const float* __restrict__ fg,
                          const float* __restrict__ fbeta, float* __restrict__ ssF) {
  int t = threadIdx.x;
  int seg = t >> 7, c = t & 127;
  const float* a = accF + seg * 256;
  float mu = a[c] / (float)NPTS;
  float var = a[128 + c] / (float)NPTS - mu * mu;
  float scale = fg[c] * rsqrtf(var + EPSf);
  ssF[seg * 256 + c] = scale;
  ssF[seg * 256 + 128 + c] = fbeta[c] - mu * scale;
}

// ---------------- out = relu(bn(YF)) @ fw2^T + fb2 ----------------
__global__ __launch_bounds__(256) void finout_gemm(
    const float* __restrict__ YF0, const float* __restrict__ YF1,
    const float* __restrict__ ss, const float* __restrict__ fw2,
    const float* __restrict__ fb2, float* __restrict__ out) {
  int dir = blockIdx.y;
  const float* yf = dir ? YF1 : YF0;
  const float* ssF = ss + 512 + dir * 256;
  float* outp = out + (size_t)dir * NPTS * 64;
  __shared__ float Wl[64][129];
  __shared__ float Hl[64][65];
  __shared__ float scl[128], shf[128], bb[64];
  int t = threadIdx.x;
  if (t < 128) {
    scl[t] = ssF[t];
    shf[t] = ssF[128 + t];
  }
  if (t < 64) bb[t] = fb2[t];
#pragma unroll
  for (int i = 0; i < 32; i++) {
    int ix = t + i * 256;
    Wl[ix >> 7][ix & 127] = fw2[ix];
  }
  __syncthreads();
  int ptb = blockIdx.x * 64;
  int ty = t >> 4, tx = t & 15, r0 = ty * 4, c0 = tx * 4;
  float acc[4][4] = {};
#pragma unroll
  for (int i = 0; i < 16; i++) {
    int ix = t + i * 256;
    int row = ix >> 6, jj = ix & 63;
    float v = yf[(size_t)(ptb + row) * 128 + jj];
    Hl[row][jj] = fmaxf(scl[jj] * v + shf[jj], 0.f);
  }
  __syncthreads();
#pragma unroll 4
  for (int j = 0; j < 64; ++j) {
    float a[4], w[4];
#pragma unroll
    for (int i = 0; i < 4; i++) a[i] = Hl[r0 + i][j];
#pragma unroll
    for (int m = 0; m < 4; m++) w[m] = Wl[c0 + m][j];
#pragma unroll
    for (int i = 0; i < 4; i++)
#pragma unroll
      for (int m = 0; m < 4; m++) acc[i][m] += a[i] * w[m];
  }
  __syncthreads();
#pragma unroll
  for (int i = 0; i < 16; i++) {
    int ix = t + i * 256;
    int row = ix >> 6, jj = ix & 63;
    float v = yf[(size_t)(ptb + row) * 128 + 64 + jj];
    Hl[row][jj] = fmaxf(scl[64 + jj] * v + shf[64 + jj], 0.f);
  }
  __syncthreads();
#pragma unroll 4
  for (int j = 0; j < 64; ++j) {
    float a[4], w[4];
#pragma unroll
    for (int i = 0; i < 4; i++) a[i] = Hl[r0 + i][j];
#pragma unroll
    for (int m = 0; m < 4; m++) w[m] = Wl[c0 + m][64 + j];
#pragma unroll
    for (int i = 0; i < 4; i++)
#pragma unroll
      for (int m = 0; m < 4; m++) acc[i][m] += a[i] * w[m];
  }
#pragma unroll
  for (int i = 0; i < 4; i++) {
    float4 v = make_float4(acc[i][0] + bb[c0], acc[i][1] + bb[c0 + 1],
                           acc[i][2] + bb[c0 + 2], acc[i][3] + bb[c0 + 3]);
    *reinterpret_cast<float4*>(outp + (size_t)(ptb + r0 + i) * 64 + c0) = v;
  }
}

extern "C" void kernel_launch(void* const* d_in, const int* in_sizes, int n_in,
                              void* d_out, int out_size, void* d_ws, size_t ws_size,
                              hipStream_t stream) {
  const float* f0 = (const float*)d_in[0];
  const float* f1 = (const float*)d_in[1];
  const int* i01 = (const int*)d_in[2];
  const int* i10 = (const int*)d_in[3];
  const float* dw1 = (const float*)d_in[4];
  const float* dg = (const float*)d_in[6];
  const float* dbe = (const float*)d_in[7];
  const float* dw2 = (const float*)d_in[8];
  const float* db2 = (const float*)d_in[9];
  const float* sw1 = (const float*)d_in[10];
  const float* sg = (const float*)d_in[12];
  const float* sbe = (const float*)d_in[13];
  const float* sw2 = (const float*)d_in[14];
  const float* sb2 = (const float*)d_in[15];
  const float* fw1 = (const float*)d_in[16];
  const float* fg = (const float*)d_in[18];
  const float* fbe = (const float*)d_in[19];
  const float* fw2 = (const float*)d_in[20];
  const float* fb2 = (const float*)d_in[21];

  char* wsb = (char*)d_ws;
  float* out = (float*)d_out;

  char* FT0 = wsb;                            // 16 MB (32768*512)
  char* FT1 = wsb + (size_t)NPTS * FT_STRIDE; // 16 MB
  float* acc = (float*)(wsb + 2 * (size_t)NPTS * FT_STRIDE);  // @32MB
  float* ss = acc + 2048;
  float* YS0 = (float*)(wsb + 2 * (size_t)NPTS * FT_STRIDE + 65536);
  float* YS1 = YS0 + GSZ;
  float* DF0 = YS1 + GSZ;
  float* DF1 = DF0 + GSZ;
  float* SF0 = DF1 + GSZ;
  float* SF1 = SF0 + GSZ;
  float* YF0 = YS0;         // 16MB over YS0+YS1 (dead after simfeat_gemm)
  float* YF1 = (float*)FT0; // 16MB over FT0 (dead after diff_out_k)

  hipMemsetAsync(acc, 0, 1024 * sizeof(float), stream);
  gemmG<<<dim3(512, 1, 2), 256, 0, stream>>>(f0, f1, dw1, sw1, FT0, FT1);

  stats_sim<<<4096, 256, 0, stream>>>(FT0, FT1, i01, i10, YS0, YS1, acc);

  finalize1<<<1, 256, 0, stream>>>(acc, dg, dbe, sg, sbe, ss);

  diff_out_k<<<4096, 256, 0, stream>>>(FT0, FT1, i01, i10, dw2, db2, ss, DF0, DF1);

  simfeat_gemm<<<dim3(512, 2), 256, 0, stream>>>(YS0, YS1, ss, sw2, sb2, SF0, SF1);

  yfin_gemm<<<dim3(512, 2, 2), 256, 0, stream>>>(DF0, DF1, SF0, SF1, fw1, YF0, YF1, acc);

  finalize2<<<1, 256, 0, stream>>>(acc + 512, fg, fbe, ss + 512);

  finout_gemm<<<dim3(512, 2), 256, 0, stream>>>(YF0, YF1, ss, fw2, fb2, out);
}